// Round 1
// baseline (523.268 us; speedup 1.0000x reference)
//
#include <hip/hip_runtime.h>
#include <hip/hip_bf16.h>

typedef short bf16x8 __attribute__((ext_vector_type(8)));
typedef float f32x4 __attribute__((ext_vector_type(4)));

static __device__ __forceinline__ unsigned short f2bf(float f) {
  unsigned int u = __builtin_bit_cast(unsigned int, f);
  u += 0x7fffu + ((u >> 16) & 1u);
  return (unsigned short)(u >> 16);
}
static __device__ __forceinline__ float bf2f(unsigned short b) {
  unsigned int u = ((unsigned int)b) << 16;
  return __builtin_bit_cast(float, u);
}

// ---------------- proj: h = relu(x @ Wp.T + bp), x[8192,256], Wp[128,256] ----------------
__global__ void proj_kernel(const float* __restrict__ x, const float* __restrict__ Wp,
                            const float* __restrict__ bp, float* __restrict__ h) {
  __shared__ float xs[16][256];
  int r0 = blockIdx.x * 16;
  int j = threadIdx.x;  // 0..127
  for (int t = j; t < 16 * 256; t += 128)
    xs[t >> 8][t & 255] = x[(size_t)(r0 + (t >> 8)) * 256 + (t & 255)];
  __syncthreads();
  float acc[16];
#pragma unroll
  for (int r = 0; r < 16; ++r) acc[r] = 0.f;
  const float4* wp4 = reinterpret_cast<const float4*>(Wp + (size_t)j * 256);
#pragma unroll 4
  for (int k4 = 0; k4 < 64; ++k4) {
    float4 w = wp4[k4];
#pragma unroll
    for (int r = 0; r < 16; ++r) {
      float4 xv = *reinterpret_cast<const float4*>(&xs[r][k4 * 4]);
      acc[r] = fmaf(xv.x, w.x, acc[r]);
      acc[r] = fmaf(xv.y, w.y, acc[r]);
      acc[r] = fmaf(xv.z, w.z, acc[r]);
      acc[r] = fmaf(xv.w, w.w, acc[r]);
    }
  }
  float b = bp[j];
#pragma unroll
  for (int r = 0; r < 16; ++r) {
    float v = acc[r] + b;
    h[(size_t)(r0 + r) * 128 + j] = v > 0.f ? v : 0.f;
  }
}

// ---------- whs: Wh = hin @ W.T (K=128), write WhT bf16 [F][8192], s_src/s_dst f32 ----------
template <int F>
__global__ void whs_kernel(const float* __restrict__ hin, const float* __restrict__ W,
                           const float* __restrict__ a, unsigned short* __restrict__ WhT,
                           float* __restrict__ s_src, float* __restrict__ s_dst) {
  constexpr int NW = F / 64;
  __shared__ float hs[16][128];
  __shared__ float rs[2][16][NW];
  int r0 = blockIdx.x * 16;
  int j = threadIdx.x;  // 0..F-1
  for (int t = j; t < 16 * 128; t += F) hs[t >> 7][t & 127] = hin[(size_t)r0 * 128 + t];
  __syncthreads();
  float acc[16];
#pragma unroll
  for (int r = 0; r < 16; ++r) acc[r] = 0.f;
  const float4* w4 = reinterpret_cast<const float4*>(W + (size_t)j * 128);
#pragma unroll 4
  for (int k4 = 0; k4 < 32; ++k4) {
    float4 w = w4[k4];
#pragma unroll
    for (int r = 0; r < 16; ++r) {
      float4 xv = *reinterpret_cast<const float4*>(&hs[r][k4 * 4]);
      acc[r] = fmaf(xv.x, w.x, acc[r]);
      acc[r] = fmaf(xv.y, w.y, acc[r]);
      acc[r] = fmaf(xv.z, w.z, acc[r]);
      acc[r] = fmaf(xv.w, w.w, acc[r]);
    }
  }
  float asrc = a[j], adst = a[F + j];
  int lane = j & 63, wv = j >> 6;
#pragma unroll
  for (int r = 0; r < 16; ++r) {
    WhT[(size_t)j * 8192 + r0 + r] = f2bf(acc[r]);
    float vs = acc[r] * asrc, vd = acc[r] * adst;
#pragma unroll
    for (int off = 32; off; off >>= 1) {
      vs += __shfl_xor(vs, off);
      vd += __shfl_xor(vd, off);
    }
    if (lane == 0) { rs[0][r][wv] = vs; rs[1][r][wv] = vd; }
  }
  __syncthreads();
  if (j < 16) {
    float vs = 0.f, vd = 0.f;
    for (int w = 0; w < NW; ++w) { vs += rs[0][j][w]; vd += rs[1][j][w]; }
    s_src[r0 + j] = vs;
    s_dst[r0 + j] = vd;
  }
}

// ---------------- global max of n floats (single block) ----------------
__global__ void gmax_kernel(const float* __restrict__ v, int n, float* __restrict__ out) {
  __shared__ float red[4];
  int lane = threadIdx.x & 63, wv = threadIdx.x >> 6;
  float mx = -1e30f;
  for (int i = threadIdx.x; i < n; i += 256) mx = fmaxf(mx, v[i]);
#pragma unroll
  for (int off = 32; off; off >>= 1) mx = fmaxf(mx, __shfl_xor(mx, off));
  if (lane == 0) red[wv] = mx;
  __syncthreads();
  if (threadIdx.x == 0) out[0] = fmaxf(fmaxf(red[0], red[1]), fmaxf(red[2], red[3]));
}

// ---------------- fused flash-GAT pass ----------------
// Per wave: 16 rows, column range [blockIdx.y*COLS, +COLS). A-frag = P tile (computed
// in-register), B-frag = WhT bf16. m̂ = lrelu(s_src + global_max(s_dst)) — a valid
// softmax shift (upper bound), so no rescaling, no masked-max pass.
// ADJ=true: read raw adj int32, emit mask bytes (layer 1). ADJ=false: read mask bytes.
template <int F, int COLS, bool ADJ>
__global__ __launch_bounds__(256) void attn_kernel(
    const int* __restrict__ adj, unsigned char* __restrict__ maskb,
    const float* __restrict__ s_src, const float* __restrict__ s_dst,
    const float* __restrict__ gmax, const unsigned short* __restrict__ WhT,
    float* __restrict__ pacc, float* __restrict__ pl) {
  int lane = threadIdx.x & 63;
  int wv = threadIdx.x >> 6;
  int r0 = blockIdx.x * 64 + wv * 16;
  int cbeg = blockIdx.y * COLS;
  int rsub = lane & 15;
  int kg = lane >> 4;
  int row = r0 + rsub;
  float ssrc = s_src[row];
  float e0 = ssrc + gmax[0];
  float m = e0 > 0.f ? e0 : 0.2f * e0;  // valid shift: >= every unmasked e in this row
  float lsum = 0.f;
  f32x4 acc[F / 16];
#pragma unroll
  for (int t = 0; t < F / 16; ++t) acc[t] = (f32x4)0.f;

  for (int k0 = cbeg; k0 < cbeg + COLS; k0 += 32) {
    int c = k0 + kg * 8;
    unsigned int mb;
    if (ADJ) {
      const int4* ap = reinterpret_cast<const int4*>(adj + (size_t)row * 8192 + c);
      int4 a0 = ap[0], a1 = ap[1];
      mb = (unsigned)((a0.x > 0) | ((a0.y > 0) << 1) | ((a0.z > 0) << 2) | ((a0.w > 0) << 3) |
                      ((a1.x > 0) << 4) | ((a1.y > 0) << 5) | ((a1.z > 0) << 6) | ((a1.w > 0) << 7));
      maskb[(size_t)row * 1024 + (c >> 3)] = (unsigned char)mb;
    } else {
      mb = maskb[(size_t)row * 1024 + (c >> 3)];
    }
    float4 sd0 = *reinterpret_cast<const float4*>(s_dst + c);
    float4 sd1 = *reinterpret_cast<const float4*>(s_dst + c + 4);
    float sds[8] = {sd0.x, sd0.y, sd0.z, sd0.w, sd1.x, sd1.y, sd1.z, sd1.w};
    bf16x8 af;
#pragma unroll
    for (int jj = 0; jj < 8; ++jj) {
      float e = ssrc + sds[jj];
      e = e > 0.f ? e : 0.2f * e;
      float p = __expf(e - m);
      p = ((mb >> jj) & 1u) ? p : 0.f;
      unsigned short pb = f2bf(p);
      af[jj] = (short)pb;
      lsum += bf2f(pb);  // sum the SAME rounded weights the MFMA consumes
    }
#pragma unroll
    for (int t = 0; t < F / 16; ++t) {
      bf16x8 bf = *reinterpret_cast<const bf16x8*>(WhT + (size_t)(t * 16 + rsub) * 8192 + c);
      acc[t] = __builtin_amdgcn_mfma_f32_16x16x32_bf16(af, bf, acc[t], 0, 0, 0);
    }
  }
  lsum += __shfl_xor(lsum, 16);
  lsum += __shfl_xor(lsum, 32);
  if (lane < 16) pl[(size_t)blockIdx.y * 8192 + r0 + lane] = lsum;
#pragma unroll
  for (int t = 0; t < F / 16; ++t) {
    int col = t * 16 + rsub;
#pragma unroll
    for (int q = 0; q < 4; ++q) {
      int ro = r0 + kg * 4 + q;  // C/D mapping: col=lane&15, row=(lane>>4)*4+reg
      pacc[(size_t)blockIdx.y * 8192 * F + (size_t)ro * F + col] = acc[t][q];
    }
  }
}

// ---------------- epilogue: out = (sum_ns pacc) / (sum_ns l), optional ELU ----------------
template <int F, bool ELU>
__global__ void epi_kernel(const float* __restrict__ pacc, const float* __restrict__ pl,
                           float* __restrict__ out) {
  int idx = blockIdx.x * 256 + threadIdx.x;
  int row = idx / F;
  float l = pl[row] + pl[8192 + row] + pl[2 * 8192 + row] + pl[3 * 8192 + row];
  float a = pacc[idx] + pacc[(size_t)8192 * F + idx] + pacc[(size_t)2 * 8192 * F + idx] +
            pacc[(size_t)3 * 8192 * F + idx];
  float v = a / l;
  if (ELU) v = v > 0.f ? v : expm1f(v);
  out[idx] = v;
}

extern "C" void kernel_launch(void* const* d_in, const int* in_sizes, int n_in,
                              void* d_out, int out_size, void* d_ws, size_t ws_size,
                              hipStream_t stream) {
  const float* x  = (const float*)d_in[0];
  const int* adj  = (const int*)d_in[1];
  const float* Wp = (const float*)d_in[2];
  const float* bp = (const float*)d_in[3];
  const float* W1 = (const float*)d_in[4];
  const float* a1 = (const float*)d_in[5];
  const float* W2 = (const float*)d_in[6];
  const float* a2 = (const float*)d_in[7];
  float* out = (float*)d_out;

  char* ws = (char*)d_ws;
  float* h            = (float*)(ws + 0);                       // 4 MB
  unsigned short* WhT1 = (unsigned short*)(ws + (4u << 20));    // 2 MB
  unsigned short* WhT2 = (unsigned short*)(ws + (6u << 20));    // 1 MB
  float* s_src1 = (float*)(ws + (7u << 20));
  float* s_dst1 = (float*)(ws + (7u << 20) + 32768);
  float* gm1    = (float*)(ws + (7u << 20) + 2 * 32768);
  float* s_src2 = (float*)(ws + (7u << 20) + 3 * 32768);
  float* s_dst2 = (float*)(ws + (7u << 20) + 4 * 32768);
  float* gm2    = (float*)(ws + (7u << 20) + 5 * 32768);
  float* pl1    = (float*)(ws + (7u << 20) + 6 * 32768);        // 128 KB
  float* pl2    = (float*)(ws + (7u << 20) + 6 * 32768 + 131072);
  unsigned char* maskb = (unsigned char*)(ws + (8u << 20));     // 8 MB
  float* pacc1  = (float*)(ws + (16u << 20));                   // 16 MB
  float* pacc2  = (float*)(ws + (32u << 20));                   // 8 MB
  float* h1     = (float*)(ws + (40u << 20));                   // 4 MB

  proj_kernel<<<512, 128, 0, stream>>>(x, Wp, bp, h);
  whs_kernel<128><<<512, 128, 0, stream>>>(h, W1, a1, WhT1, s_src1, s_dst1);
  gmax_kernel<<<1, 256, 0, stream>>>(s_dst1, 8192, gm1);
  attn_kernel<128, 2048, true><<<dim3(128, 4), 256, 0, stream>>>(
      adj, maskb, s_src1, s_dst1, gm1, WhT1, pacc1, pl1);
  epi_kernel<128, true><<<4096, 256, 0, stream>>>(pacc1, pl1, h1);
  whs_kernel<64><<<512, 64, 0, stream>>>(h1, W2, a2, WhT2, s_src2, s_dst2);
  gmax_kernel<<<1, 256, 0, stream>>>(s_dst2, 8192, gm2);
  attn_kernel<64, 2048, false><<<dim3(128, 4), 256, 0, stream>>>(
      adj, maskb, s_src2, s_dst2, gm2, WhT2, pacc2, pl2);
  epi_kernel<64, false><<<2048, 256, 0, stream>>>(pacc2, pl2, out);
}

// Round 2
// 407.992 us; speedup vs baseline: 1.2825x; 1.2825x over previous
//
#include <hip/hip_runtime.h>
#include <hip/hip_bf16.h>

typedef short bf16x8 __attribute__((ext_vector_type(8)));
typedef float f32x4 __attribute__((ext_vector_type(4)));

static __device__ __forceinline__ unsigned short f2bf(float f) {
  unsigned int u = __builtin_bit_cast(unsigned int, f);
  u += 0x7fffu + ((u >> 16) & 1u);
  return (unsigned short)(u >> 16);
}
static __device__ __forceinline__ float bf2f(unsigned short b) {
  unsigned int u = ((unsigned int)b) << 16;
  return __builtin_bit_cast(float, u);
}

// ---------------- proj: h = relu(x @ Wp.T + bp), x[8192,256], Wp[128,256] ----------------
__global__ void proj_kernel(const float* __restrict__ x, const float* __restrict__ Wp,
                            const float* __restrict__ bp, float* __restrict__ h) {
  __shared__ float xs[16][256];
  int r0 = blockIdx.x * 16;
  int j = threadIdx.x;  // 0..127
  for (int t = j; t < 16 * 256; t += 128)
    xs[t >> 8][t & 255] = x[(size_t)(r0 + (t >> 8)) * 256 + (t & 255)];
  __syncthreads();
  float acc[16];
#pragma unroll
  for (int r = 0; r < 16; ++r) acc[r] = 0.f;
  const float4* wp4 = reinterpret_cast<const float4*>(Wp + (size_t)j * 256);
#pragma unroll 4
  for (int k4 = 0; k4 < 64; ++k4) {
    float4 w = wp4[k4];
#pragma unroll
    for (int r = 0; r < 16; ++r) {
      float4 xv = *reinterpret_cast<const float4*>(&xs[r][k4 * 4]);
      acc[r] = fmaf(xv.x, w.x, acc[r]);
      acc[r] = fmaf(xv.y, w.y, acc[r]);
      acc[r] = fmaf(xv.z, w.z, acc[r]);
      acc[r] = fmaf(xv.w, w.w, acc[r]);
    }
  }
  float b = bp[j];
#pragma unroll
  for (int r = 0; r < 16; ++r) {
    float v = acc[r] + b;
    h[(size_t)(r0 + r) * 128 + j] = v > 0.f ? v : 0.f;
  }
}

// ---------- whs: Wh = hin @ W.T (K=128), write WhT bf16 [F][8192], s_src/s_dst f32 ----------
template <int F>
__global__ void whs_kernel(const float* __restrict__ hin, const float* __restrict__ W,
                           const float* __restrict__ a, unsigned short* __restrict__ WhT,
                           float* __restrict__ s_src, float* __restrict__ s_dst) {
  constexpr int NW = F / 64;
  __shared__ float hs[16][128];
  __shared__ float rs[2][16][NW];
  int r0 = blockIdx.x * 16;
  int j = threadIdx.x;  // 0..F-1
  for (int t = j; t < 16 * 128; t += F) hs[t >> 7][t & 127] = hin[(size_t)r0 * 128 + t];
  __syncthreads();
  float acc[16];
#pragma unroll
  for (int r = 0; r < 16; ++r) acc[r] = 0.f;
  const float4* w4 = reinterpret_cast<const float4*>(W + (size_t)j * 128);
#pragma unroll 4
  for (int k4 = 0; k4 < 32; ++k4) {
    float4 w = w4[k4];
#pragma unroll
    for (int r = 0; r < 16; ++r) {
      float4 xv = *reinterpret_cast<const float4*>(&hs[r][k4 * 4]);
      acc[r] = fmaf(xv.x, w.x, acc[r]);
      acc[r] = fmaf(xv.y, w.y, acc[r]);
      acc[r] = fmaf(xv.z, w.z, acc[r]);
      acc[r] = fmaf(xv.w, w.w, acc[r]);
    }
  }
  float asrc = a[j], adst = a[F + j];
  int lane = j & 63, wv = j >> 6;
#pragma unroll
  for (int r = 0; r < 16; ++r) {
    WhT[(size_t)j * 8192 + r0 + r] = f2bf(acc[r]);
    float vs = acc[r] * asrc, vd = acc[r] * adst;
#pragma unroll
    for (int off = 32; off; off >>= 1) {
      vs += __shfl_xor(vs, off);
      vd += __shfl_xor(vd, off);
    }
    if (lane == 0) { rs[0][r][wv] = vs; rs[1][r][wv] = vd; }
  }
  __syncthreads();
  if (j < 16) {
    float vs = 0.f, vd = 0.f;
    for (int w = 0; w < NW; ++w) { vs += rs[0][j][w]; vd += rs[1][j][w]; }
    s_src[r0 + j] = vs;
    s_dst[r0 + j] = vd;
  }
}

// ---------------- global max of n floats (single block) ----------------
__global__ void gmax_kernel(const float* __restrict__ v, int n, float* __restrict__ out) {
  __shared__ float red[4];
  int lane = threadIdx.x & 63, wv = threadIdx.x >> 6;
  float mx = -1e30f;
  for (int i = threadIdx.x; i < n; i += 256) mx = fmaxf(mx, v[i]);
#pragma unroll
  for (int off = 32; off; off >>= 1) mx = fmaxf(mx, __shfl_xor(mx, off));
  if (lane == 0) red[wv] = mx;
  __syncthreads();
  if (threadIdx.x == 0) out[0] = fmaxf(fmaxf(red[0], red[1]), fmaxf(red[2], red[3]));
}

// ---------------- fused flash-GAT pass ----------------
// Per wave: 16 rows, runtime column range [blockIdx.y*cps, +cps). A-frag = P tile
// (computed in-register), B-frag = WhT bf16. m̂ = lrelu(s_src + global_max(s_dst))
// is a valid softmax shift (upper bound) -> no rescaling, no masked-max pass.
// 2-deep software prefetch on adj/mask/s_dst to overlap HBM latency with exp+MFMA.
template <int F, bool ADJ>
__global__ __launch_bounds__(256) void attn_kernel(
    const int* __restrict__ adj, unsigned char* __restrict__ maskb,
    const float* __restrict__ s_src, const float* __restrict__ s_dst,
    const float* __restrict__ gmax, const unsigned short* __restrict__ WhT,
    float* __restrict__ pacc, float* __restrict__ pl, int cps) {
  int lane = threadIdx.x & 63;
  int wv = threadIdx.x >> 6;
  int r0 = blockIdx.x * 64 + wv * 16;
  int cbeg = blockIdx.y * cps;
  int cend = cbeg + cps;
  int rsub = lane & 15;
  int kg = lane >> 4;
  int row = r0 + rsub;
  float ssrc = s_src[row];
  float e0 = ssrc + gmax[0];
  float m = e0 > 0.f ? e0 : 0.2f * e0;  // valid shift: >= every unmasked e in this row
  float lsum = 0.f;
  f32x4 acc[F / 16];
#pragma unroll
  for (int t = 0; t < F / 16; ++t) acc[t] = (f32x4)0.f;

  const int4* ap = reinterpret_cast<const int4*>(adj + (size_t)row * 8192);
  unsigned char* mrow = maskb + (size_t)row * 1024;

  // ---- prefetch iteration 0 ----
  int c0 = cbeg + kg * 8;
  int4 pa0, pa1;
  unsigned int pmb = 0;
  if (ADJ) {
    pa0 = ap[c0 >> 2];
    pa1 = ap[(c0 >> 2) + 1];
  } else {
    pmb = mrow[c0 >> 3];
  }
  float4 psd0 = *reinterpret_cast<const float4*>(s_dst + c0);
  float4 psd1 = *reinterpret_cast<const float4*>(s_dst + c0 + 4);

  for (int k0 = cbeg; k0 < cend; k0 += 32) {
    int c = k0 + kg * 8;
    bool more = (k0 + 32) < cend;
    unsigned int mb;
    float4 sd0 = psd0, sd1 = psd1;
    if (ADJ) {
      int4 a0 = pa0, a1 = pa1;
      if (more) {  // issue next iteration's adj load NOW (overlaps exp+MFMA below)
        pa0 = ap[(c + 32) >> 2];
        pa1 = ap[((c + 32) >> 2) + 1];
      }
      mb = (unsigned)((a0.x > 0) | ((a0.y > 0) << 1) | ((a0.z > 0) << 2) | ((a0.w > 0) << 3) |
                      ((a1.x > 0) << 4) | ((a1.y > 0) << 5) | ((a1.z > 0) << 6) |
                      ((a1.w > 0) << 7));
      mrow[c >> 3] = (unsigned char)mb;
    } else {
      mb = pmb;
      if (more) pmb = mrow[(c + 32) >> 3];
    }
    if (more) {
      psd0 = *reinterpret_cast<const float4*>(s_dst + c + 32);
      psd1 = *reinterpret_cast<const float4*>(s_dst + c + 36);
    }
    float sds[8] = {sd0.x, sd0.y, sd0.z, sd0.w, sd1.x, sd1.y, sd1.z, sd1.w};
    bf16x8 af;
#pragma unroll
    for (int jj = 0; jj < 8; ++jj) {
      float e = ssrc + sds[jj];
      e = e > 0.f ? e : 0.2f * e;
      float p = __expf(e - m);
      p = ((mb >> jj) & 1u) ? p : 0.f;
      unsigned short pb = f2bf(p);
      af[jj] = (short)pb;
      lsum += bf2f(pb);  // sum the SAME rounded weights the MFMA consumes
    }
#pragma unroll
    for (int t = 0; t < F / 16; ++t) {
      bf16x8 bf = *reinterpret_cast<const bf16x8*>(WhT + (size_t)(t * 16 + rsub) * 8192 + c);
      acc[t] = __builtin_amdgcn_mfma_f32_16x16x32_bf16(af, bf, acc[t], 0, 0, 0);
    }
  }
  lsum += __shfl_xor(lsum, 16);
  lsum += __shfl_xor(lsum, 32);
  if (lane < 16) pl[(size_t)blockIdx.y * 8192 + r0 + lane] = lsum;
#pragma unroll
  for (int t = 0; t < F / 16; ++t) {
    int col = t * 16 + rsub;
#pragma unroll
    for (int q = 0; q < 4; ++q) {
      int ro = r0 + kg * 4 + q;  // C/D mapping: col=lane&15, row=(lane>>4)*4+reg
      pacc[(size_t)blockIdx.y * 8192 * F + (size_t)ro * F + col] = acc[t][q];
    }
  }
}

// -------- epilogue: out = (sum_s pacc) / (sum_s l), optional ELU, runtime S --------
template <int F, bool ELU>
__global__ void epi_kernel(const float* __restrict__ pacc, const float* __restrict__ pl,
                           float* __restrict__ out, int S) {
  int idx = blockIdx.x * 256 + threadIdx.x;
  int row = idx / F;
  float l = 0.f, a = 0.f;
  for (int s = 0; s < S; ++s) {
    l += pl[(size_t)s * 8192 + row];
    a += pacc[(size_t)s * 8192 * F + idx];
  }
  float v = a / l;
  if (ELU) v = v > 0.f ? v : expm1f(v);
  out[idx] = v;
}

extern "C" void kernel_launch(void* const* d_in, const int* in_sizes, int n_in,
                              void* d_out, int out_size, void* d_ws, size_t ws_size,
                              hipStream_t stream) {
  const float* x  = (const float*)d_in[0];
  const int* adj  = (const int*)d_in[1];
  const float* Wp = (const float*)d_in[2];
  const float* bp = (const float*)d_in[3];
  const float* W1 = (const float*)d_in[4];
  const float* a1 = (const float*)d_in[5];
  const float* W2 = (const float*)d_in[6];
  const float* a2 = (const float*)d_in[7];
  float* out = (float*)d_out;

  // column-split count, bounded by workspace: need 22MB + S*6MB
  int S = 4;
  if (ws_size >= (size_t)(22 + 16 * 6) * 1024 * 1024) S = 16;
  else if (ws_size >= (size_t)(22 + 8 * 6) * 1024 * 1024) S = 8;
  int cps = 8192 / S;

  char* ws = (char*)d_ws;
  float* h             = (float*)(ws + 0);                      // 4 MB
  unsigned short* WhT1 = (unsigned short*)(ws + (4u << 20));    // 2 MB
  unsigned short* WhT2 = (unsigned short*)(ws + (6u << 20));    // 1 MB
  float* s_src1 = (float*)(ws + (7u << 20));
  float* s_dst1 = (float*)(ws + (7u << 20) + (64u << 10));
  float* s_src2 = (float*)(ws + (7u << 20) + (128u << 10));
  float* s_dst2 = (float*)(ws + (7u << 20) + (192u << 10));
  float* gm1    = (float*)(ws + (7u << 20) + (256u << 10));
  float* gm2    = (float*)(ws + (7u << 20) + (260u << 10));
  unsigned char* maskb = (unsigned char*)(ws + (8u << 20));     // 8 MB
  float* h1     = (float*)(ws + (16u << 20));                   // 4 MB
  float* pl1    = (float*)(ws + (20u << 20));                   // up to 512 KB
  float* pl2    = (float*)(ws + (21u << 20));                   // up to 512 KB
  float* pacc1  = (float*)(ws + (22u << 20));                   // S*4 MB
  float* pacc2  = (float*)(ws + (22u << 20) + (size_t)S * (4u << 20));  // S*2 MB

  proj_kernel<<<512, 128, 0, stream>>>(x, Wp, bp, h);
  whs_kernel<128><<<512, 128, 0, stream>>>(h, W1, a1, WhT1, s_src1, s_dst1);
  gmax_kernel<<<1, 256, 0, stream>>>(s_dst1, 8192, gm1);
  attn_kernel<128, true><<<dim3(128, S), 256, 0, stream>>>(
      adj, maskb, s_src1, s_dst1, gm1, WhT1, pacc1, pl1, cps);
  epi_kernel<128, true><<<4096, 256, 0, stream>>>(pacc1, pl1, h1, S);
  whs_kernel<64><<<512, 64, 0, stream>>>(h1, W2, a2, WhT2, s_src2, s_dst2);
  gmax_kernel<<<1, 256, 0, stream>>>(s_dst2, 8192, gm2);
  attn_kernel<64, false><<<dim3(128, S), 256, 0, stream>>>(
      adj, maskb, s_src2, s_dst2, gm2, WhT2, pacc2, pl2, cps);
  epi_kernel<64, false><<<2048, 256, 0, stream>>>(pacc2, pl2, out, S);
}

// Round 3
// 372.375 us; speedup vs baseline: 1.4052x; 1.0956x over previous
//
#include <hip/hip_runtime.h>
#include <hip/hip_bf16.h>

typedef short bf16x8 __attribute__((ext_vector_type(8)));
typedef float f32x4 __attribute__((ext_vector_type(4)));

static __device__ __forceinline__ unsigned short f2bf(float f) {
  unsigned int u = __builtin_bit_cast(unsigned int, f);
  u += 0x7fffu + ((u >> 16) & 1u);
  return (unsigned short)(u >> 16);
}
static __device__ __forceinline__ float bf2f(unsigned short b) {
  unsigned int u = ((unsigned int)b) << 16;
  return __builtin_bit_cast(float, u);
}

// ---------------- proj: h = relu(x @ Wp.T + bp), x[8192,256], Wp[128,256] ----------------
__global__ void proj_kernel(const float* __restrict__ x, const float* __restrict__ Wp,
                            const float* __restrict__ bp, float* __restrict__ h) {
  __shared__ float xs[16][256];
  int r0 = blockIdx.x * 16;
  int j = threadIdx.x;  // 0..127
  for (int t = j; t < 16 * 256; t += 128)
    xs[t >> 8][t & 255] = x[(size_t)(r0 + (t >> 8)) * 256 + (t & 255)];
  __syncthreads();
  float acc[16];
#pragma unroll
  for (int r = 0; r < 16; ++r) acc[r] = 0.f;
  const float4* wp4 = reinterpret_cast<const float4*>(Wp + (size_t)j * 256);
#pragma unroll 4
  for (int k4 = 0; k4 < 64; ++k4) {
    float4 w = wp4[k4];
#pragma unroll
    for (int r = 0; r < 16; ++r) {
      float4 xv = *reinterpret_cast<const float4*>(&xs[r][k4 * 4]);
      acc[r] = fmaf(xv.x, w.x, acc[r]);
      acc[r] = fmaf(xv.y, w.y, acc[r]);
      acc[r] = fmaf(xv.z, w.z, acc[r]);
      acc[r] = fmaf(xv.w, w.w, acc[r]);
    }
  }
  float b = bp[j];
#pragma unroll
  for (int r = 0; r < 16; ++r) {
    float v = acc[r] + b;
    h[(size_t)(r0 + r) * 128 + j] = v > 0.f ? v : 0.f;
  }
}

// ---------- whs: Wh = hin @ W.T (K=128), write WhT bf16 [F][8192], s_src/s_dst f32 ----------
template <int F>
__global__ void whs_kernel(const float* __restrict__ hin, const float* __restrict__ W,
                           const float* __restrict__ a, unsigned short* __restrict__ WhT,
                           float* __restrict__ s_src, float* __restrict__ s_dst) {
  constexpr int NW = F / 64;
  __shared__ float hs[16][128];
  __shared__ float rs[2][16][NW];
  int r0 = blockIdx.x * 16;
  int j = threadIdx.x;  // 0..F-1
  for (int t = j; t < 16 * 128; t += F) hs[t >> 7][t & 127] = hin[(size_t)r0 * 128 + t];
  __syncthreads();
  float acc[16];
#pragma unroll
  for (int r = 0; r < 16; ++r) acc[r] = 0.f;
  const float4* w4 = reinterpret_cast<const float4*>(W + (size_t)j * 128);
#pragma unroll 4
  for (int k4 = 0; k4 < 32; ++k4) {
    float4 w = w4[k4];
#pragma unroll
    for (int r = 0; r < 16; ++r) {
      float4 xv = *reinterpret_cast<const float4*>(&hs[r][k4 * 4]);
      acc[r] = fmaf(xv.x, w.x, acc[r]);
      acc[r] = fmaf(xv.y, w.y, acc[r]);
      acc[r] = fmaf(xv.z, w.z, acc[r]);
      acc[r] = fmaf(xv.w, w.w, acc[r]);
    }
  }
  float asrc = a[j], adst = a[F + j];
  int lane = j & 63, wv = j >> 6;
#pragma unroll
  for (int r = 0; r < 16; ++r) {
    WhT[(size_t)j * 8192 + r0 + r] = f2bf(acc[r]);
    float vs = acc[r] * asrc, vd = acc[r] * adst;
#pragma unroll
    for (int off = 32; off; off >>= 1) {
      vs += __shfl_xor(vs, off);
      vd += __shfl_xor(vd, off);
    }
    if (lane == 0) { rs[0][r][wv] = vs; rs[1][r][wv] = vd; }
  }
  __syncthreads();
  if (j < 16) {
    float vs = 0.f, vd = 0.f;
    for (int w = 0; w < NW; ++w) { vs += rs[0][j][w]; vd += rs[1][j][w]; }
    s_src[r0 + j] = vs;
    s_dst[r0 + j] = vd;
  }
}

// ---------------- global max of n floats (single block) ----------------
__global__ void gmax_kernel(const float* __restrict__ v, int n, float* __restrict__ out) {
  __shared__ float red[4];
  int lane = threadIdx.x & 63, wv = threadIdx.x >> 6;
  float mx = -1e30f;
  for (int i = threadIdx.x; i < n; i += 256) mx = fmaxf(mx, v[i]);
#pragma unroll
  for (int off = 32; off; off >>= 1) mx = fmaxf(mx, __shfl_xor(mx, off));
  if (lane == 0) red[wv] = mx;
  __syncthreads();
  if (threadIdx.x == 0) out[0] = fmaxf(fmaxf(red[0], red[1]), fmaxf(red[2], red[3]));
}

// ---------------- fused flash-GAT pass ----------------
// Wave: 16 rows x [blockIdx.y*cps, +cps) cols. m̂ = lrelu(s_src + gmax(s_dst)) is an
// upper-bound softmax shift -> no rescale. Row-sum l via MFMA with ones-B (exact:
// same bf16 weights, f32 accumulate). Unroll-by-2 pipeline, prefetch distance = 2
// column-windows (64 cols) on the adj/mask HBM stream. Partials stored bf16.
template <int F, bool ADJ>
__global__ __launch_bounds__(256) void attn_kernel(
    const int* __restrict__ adj, unsigned char* __restrict__ maskb,
    const float* __restrict__ s_src, const float* __restrict__ s_dst,
    const float* __restrict__ gmax, const unsigned short* __restrict__ WhT,
    unsigned short* __restrict__ pacc, float* __restrict__ pl, int cps) {
  int lane = threadIdx.x & 63;
  int wv = threadIdx.x >> 6;
  int r0 = blockIdx.x * 64 + wv * 16;
  int cbeg = blockIdx.y * cps;
  int cend = cbeg + cps;
  int rsub = lane & 15;
  int kg = lane >> 4;
  int row = r0 + rsub;
  float ssrc = s_src[row];
  float e0 = ssrc + gmax[0];
  float m = fmaxf(e0, 0.2f * e0);  // valid shift: >= every unmasked e in this row
  f32x4 acc[F / 16];
#pragma unroll
  for (int t = 0; t < F / 16; ++t) acc[t] = (f32x4)0.f;
  f32x4 accl = (f32x4)0.f;
  bf16x8 ones;
#pragma unroll
  for (int jj = 0; jj < 8; ++jj) ones[jj] = (short)0x3F80;  // bf16 1.0

  const int4* ap = reinterpret_cast<const int4*>(adj + (size_t)row * 8192);
  unsigned char* mrow = maskb + (size_t)row * 1024;

#define GAT_BODY(CC, MB)                                                                   \
  {                                                                                        \
    float4 sd0 = *reinterpret_cast<const float4*>(s_dst + (CC));                           \
    float4 sd1 = *reinterpret_cast<const float4*>(s_dst + (CC) + 4);                       \
    float sds[8] = {sd0.x, sd0.y, sd0.z, sd0.w, sd1.x, sd1.y, sd1.z, sd1.w};               \
    bf16x8 af;                                                                             \
    _Pragma("unroll") for (int jj = 0; jj < 8; ++jj) {                                     \
      float e = ssrc + sds[jj];                                                            \
      e = fmaxf(e, 0.2f * e);                                                              \
      float p = __expf(e - m);                                                             \
      p = (((MB) >> jj) & 1u) ? p : 0.f;                                                   \
      af[jj] = (short)f2bf(p);                                                             \
    }                                                                                      \
    accl = __builtin_amdgcn_mfma_f32_16x16x32_bf16(af, ones, accl, 0, 0, 0);               \
    _Pragma("unroll") for (int t = 0; t < F / 16; ++t) {                                   \
      bf16x8 bf = *reinterpret_cast<const bf16x8*>(WhT + (size_t)(t * 16 + rsub) * 8192 +  \
                                                   (CC));                                  \
      acc[t] = __builtin_amdgcn_mfma_f32_16x16x32_bf16(af, bf, acc[t], 0, 0, 0);           \
    }                                                                                      \
  }

  int c = cbeg + kg * 8;
  // pipeline prologue: stage X = window k0, stage Y = window k0+32
  int4 xa0, xa1, ya0, ya1;
  unsigned int xm = 0, ym = 0;
  if (ADJ) {
    xa0 = ap[c >> 2];
    xa1 = ap[(c >> 2) + 1];
    ya0 = ap[(c + 32) >> 2];
    ya1 = ap[((c + 32) >> 2) + 1];
  } else {
    xm = mrow[c >> 3];
    ym = mrow[(c + 32) >> 3];
  }

  for (int k0 = cbeg; k0 < cend; k0 += 64) {
    // ---- stage X (window k0, lane col c) ----
    {
      unsigned int mb;
      if (ADJ) {
        mb = (unsigned)((xa0.x > 0) | ((xa0.y > 0) << 1) | ((xa0.z > 0) << 2) |
                        ((xa0.w > 0) << 3) | ((xa1.x > 0) << 4) | ((xa1.y > 0) << 5) |
                        ((xa1.z > 0) << 6) | ((xa1.w > 0) << 7));
        int cn = (k0 + 64 < cend) ? c + 64 : c;  // prefetch 2 windows ahead (clamped)
        xa0 = ap[cn >> 2];
        xa1 = ap[(cn >> 2) + 1];
        mrow[c >> 3] = (unsigned char)mb;
      } else {
        mb = xm;
        int cn = (k0 + 64 < cend) ? c + 64 : c;
        xm = mrow[cn >> 3];
      }
      GAT_BODY(c, mb)
    }
    // ---- stage Y (window k0+32, lane col c+32) ----
    {
      unsigned int mb;
      if (ADJ) {
        mb = (unsigned)((ya0.x > 0) | ((ya0.y > 0) << 1) | ((ya0.z > 0) << 2) |
                        ((ya0.w > 0) << 3) | ((ya1.x > 0) << 4) | ((ya1.y > 0) << 5) |
                        ((ya1.z > 0) << 6) | ((ya1.w > 0) << 7));
        int cn = (k0 + 96 < cend) ? c + 96 : c;
        ya0 = ap[cn >> 2];
        ya1 = ap[(cn >> 2) + 1];
        mrow[(c + 32) >> 3] = (unsigned char)mb;
      } else {
        mb = ym;
        int cn = (k0 + 96 < cend) ? c + 96 : c;
        ym = mrow[cn >> 3];
      }
      GAT_BODY(c + 32, mb)
    }
    c += 64;
  }
#undef GAT_BODY

  // row-sums: accl D[row][col] with all cols equal; lane rsub==0 of each kg group
  // holds rows kg*4+q in accl[q]
  if (rsub == 0) {
#pragma unroll
    for (int q = 0; q < 4; ++q)
      pl[(size_t)blockIdx.y * 8192 + r0 + kg * 4 + q] = accl[q];
  }
#pragma unroll
  for (int t = 0; t < F / 16; ++t) {
    int col = t * 16 + rsub;
#pragma unroll
    for (int q = 0; q < 4; ++q) {
      int ro = r0 + kg * 4 + q;  // C/D mapping: col=lane&15, row=(lane>>4)*4+reg
      pacc[(size_t)blockIdx.y * 8192 * F + (size_t)ro * F + col] = f2bf(acc[t][q]);
    }
  }
}

// -------- epilogue: out = (sum_s pacc) / (sum_s l), optional ELU, runtime S --------
template <int F, bool ELU>
__global__ void epi_kernel(const unsigned short* __restrict__ pacc,
                           const float* __restrict__ pl, float* __restrict__ out, int S) {
  int idx = blockIdx.x * 256 + threadIdx.x;
  int row = idx / F;
  float l = 0.f, a = 0.f;
  for (int s = 0; s < S; ++s) {
    l += pl[(size_t)s * 8192 + row];
    a += bf2f(pacc[(size_t)s * 8192 * F + idx]);
  }
  float v = a / l;
  if (ELU) v = v > 0.f ? v : expm1f(v);
  out[idx] = v;
}

extern "C" void kernel_launch(void* const* d_in, const int* in_sizes, int n_in,
                              void* d_out, int out_size, void* d_ws, size_t ws_size,
                              hipStream_t stream) {
  const float* x  = (const float*)d_in[0];
  const int* adj  = (const int*)d_in[1];
  const float* Wp = (const float*)d_in[2];
  const float* bp = (const float*)d_in[3];
  const float* W1 = (const float*)d_in[4];
  const float* a1 = (const float*)d_in[5];
  const float* W2 = (const float*)d_in[6];
  const float* a2 = (const float*)d_in[7];
  float* out = (float*)d_out;

  // workspace: fixed 21 MiB + S*(2+1) MiB (bf16 partials)
  int S = 4;
  if (ws_size >= (21ull + 16 * 3) * 1024 * 1024) S = 16;
  else if (ws_size >= (21ull + 8 * 3) * 1024 * 1024) S = 8;
  int cps = 8192 / S;

  char* ws = (char*)d_ws;
  float* h             = (float*)(ws + 0);                      // 0-4 MiB
  unsigned short* WhT1 = (unsigned short*)(ws + (4ull << 20));  // 4-6
  unsigned short* WhT2 = (unsigned short*)(ws + (6ull << 20));  // 6-7
  float* s_src1 = (float*)(ws + (7ull << 20));
  float* s_dst1 = (float*)(ws + (7ull << 20) + (64u << 10));
  float* s_src2 = (float*)(ws + (7ull << 20) + (128u << 10));
  float* s_dst2 = (float*)(ws + (7ull << 20) + (192u << 10));
  float* gm1    = (float*)(ws + (7ull << 20) + (256u << 10));
  float* gm2    = (float*)(ws + (7ull << 20) + (260u << 10));
  unsigned char* maskb = (unsigned char*)(ws + (8ull << 20));   // 8-16
  float* h1     = (float*)(ws + (16ull << 20));                 // 16-20
  float* pl1    = (float*)(ws + (20ull << 20));                 // 20-20.5
  float* pl2    = (float*)(ws + (20ull << 20) + (512u << 10));  // 20.5-21
  unsigned short* pacc1 = (unsigned short*)(ws + (21ull << 20));          // S*2 MiB
  unsigned short* pacc2 = pacc1 + (size_t)S * 8192 * 128;                 // S*1 MiB

  proj_kernel<<<512, 128, 0, stream>>>(x, Wp, bp, h);
  whs_kernel<128><<<512, 128, 0, stream>>>(h, W1, a1, WhT1, s_src1, s_dst1);
  gmax_kernel<<<1, 256, 0, stream>>>(s_dst1, 8192, gm1);
  attn_kernel<128, true><<<dim3(128, S), 256, 0, stream>>>(
      adj, maskb, s_src1, s_dst1, gm1, WhT1, pacc1, pl1, cps);
  epi_kernel<128, true><<<4096, 256, 0, stream>>>(pacc1, pl1, h1, S);
  whs_kernel<64><<<512, 64, 0, stream>>>(h1, W2, a2, WhT2, s_src2, s_dst2);
  gmax_kernel<<<1, 256, 0, stream>>>(s_dst2, 8192, gm2);
  attn_kernel<64, false><<<dim3(128, S), 256, 0, stream>>>(
      adj, maskb, s_src2, s_dst2, gm2, WhT2, pacc2, pl2, cps);
  epi_kernel<64, false><<<2048, 256, 0, stream>>>(pacc2, pl2, out, S);
}